// Round 7
// baseline (640.993 us; speedup 1.0000x reference)
//
#include <hip/hip_runtime.h>
#include <stdint.h>

#define NS 100000
#define NR 200000
#define EE 1000000
#define DD 128
#define NB 50
#define NSP 2000
#define NRP 4000
#define BSH 10
#define NBR 196   /* ceil(NR/1024) */
#define NBS 98    /* ceil(NS/1024) */
#define CHUNK 8192

typedef short bf16x8 __attribute__((ext_vector_type(8)));
typedef float f32x4 __attribute__((ext_vector_type(4)));
typedef float f32x2 __attribute__((ext_vector_type(2)));
typedef unsigned u32x4 __attribute__((ext_vector_type(4)));
typedef unsigned u32x2 __attribute__((ext_vector_type(2)));

__device__ __forceinline__ unsigned short f2bf(float f){
  unsigned u = __float_as_uint(f);
  u = (u + 0x7FFFu + ((u >> 16) & 1u)) >> 16;
  return (unsigned short)u;
}
__device__ __forceinline__ unsigned packbf(float a, float b){
  return (unsigned)f2bf(a) | ((unsigned)f2bf(b) << 16);
}
__device__ __forceinline__ float bflo(unsigned p){ return __uint_as_float(p << 16); }
__device__ __forceinline__ float bfhi(unsigned p){ return __uint_as_float(p & 0xFFFF0000u); }
// pack 4 floats -> 4 fp8 e4m3 (OCP) in one dword
__device__ __forceinline__ unsigned pack4fp8(float v0, float v1, float v2, float v3){
  unsigned p = __builtin_amdgcn_cvt_pk_fp8_f32(v0, v1, 0, false);
  p = __builtin_amdgcn_cvt_pk_fp8_f32(v2, v3, p, true);
  return p;
}

// accumulate 8 fp8 values (one dwordx4 quarter.. full 16B = 16 vals into P[0..7])
#define ACC8(P, D) do{ f32x2 f_; \
  f_ = __builtin_amdgcn_cvt_pk_f32_fp8((D).x,false); P[0][0]+=f_[0]; P[0][1]+=f_[1]; \
  f_ = __builtin_amdgcn_cvt_pk_f32_fp8((D).x,true ); P[1][0]+=f_[0]; P[1][1]+=f_[1]; \
  f_ = __builtin_amdgcn_cvt_pk_f32_fp8((D).y,false); P[2][0]+=f_[0]; P[2][1]+=f_[1]; \
  f_ = __builtin_amdgcn_cvt_pk_f32_fp8((D).y,true ); P[3][0]+=f_[0]; P[3][1]+=f_[1]; \
  f_ = __builtin_amdgcn_cvt_pk_f32_fp8((D).z,false); P[4][0]+=f_[0]; P[4][1]+=f_[1]; \
  f_ = __builtin_amdgcn_cvt_pk_f32_fp8((D).z,true ); P[5][0]+=f_[0]; P[5][1]+=f_[1]; \
  f_ = __builtin_amdgcn_cvt_pk_f32_fp8((D).w,false); P[6][0]+=f_[0]; P[6][1]+=f_[1]; \
  f_ = __builtin_amdgcn_cvt_pk_f32_fp8((D).w,true ); P[7][0]+=f_[0]; P[7][1]+=f_[1]; \
}while(0)

// ---------------- weight pre-pack into MFMA fragment order ----------------
// Wp[mat][ct][ks][lane][j] = W[mat][k = ks*32 + (lane>>4)*8 + j][col = ct*16 + (lane&15)]
__global__ void pack_w(const float* __restrict__ Wr, const float* __restrict__ Ws,
                       unsigned short* __restrict__ Wp){
  int g = blockIdx.x*256 + threadIdx.x;   // 4*32768 = 131072 total
  if (g >= 4*32768) return;
  int j = g & 7; int rest = g >> 3;
  int lane = rest & 63; rest >>= 6;
  int ks = rest & 7; rest >>= 3;
  int ct = rest & 7; int mat = rest >> 3;
  int k  = ks*32 + (lane >> 4)*8 + j;
  int cc = ct*16 + (lane & 15);
  const float* src = (mat < 2) ? (Wr + (size_t)mat*256*DD) : (Ws + (size_t)(mat-2)*256*DD);
  Wp[g] = f2bf(src[(size_t)k*DD + cc]);
}

// ---------------- fused embedding init: 16B stores, float4 reads ----------------
// Also emits the fp8-e4m3 shadow of h_s (gather source for layer-0 R-side).
__global__ __launch_bounds__(256) void init_all(const int* __restrict__ si, const int* __restrict__ ext,
        const int* __restrict__ tid, const float* __restrict__ pp,
        const float* __restrict__ st, const float* __restrict__ et, const float* __restrict__ tt,
        const float* __restrict__ Wpar, const float* __restrict__ bpar,
        unsigned short* __restrict__ hs, unsigned short* __restrict__ hr,
        unsigned char* __restrict__ hs8){
  int g = blockIdx.x*256 + threadIdx.x;   // (NS+NR)*16 total
  int row = g >> 4, colb = (g & 15) * 8;
  if (row < NS){
    const float* a = st + (size_t)si[row]*DD + colb;
    const float* b = et + (size_t)ext[row]*DD + colb;
    float4 x0 = ((const float4*)a)[0], x1 = ((const float4*)a)[1];
    float4 y0 = ((const float4*)b)[0], y1 = ((const float4*)b)[1];
    float s0 = x0.x+y0.x, s1 = x0.y+y0.y, s2 = x0.z+y0.z, s3 = x0.w+y0.w;
    float s4 = x1.x+y1.x, s5 = x1.y+y1.y, s6 = x1.z+y1.z, s7 = x1.w+y1.w;
    u32x4 o;
    o.x = packbf(s0, s1); o.y = packbf(s2, s3);
    o.z = packbf(s4, s5); o.w = packbf(s6, s7);
    *(u32x4*)(hs + (size_t)row*DD + colb) = o;
    u32x2 e; e.x = pack4fp8(s0, s1, s2, s3); e.y = pack4fp8(s4, s5, s6, s7);
    *(u32x2*)(hs8 + (size_t)row*DD + colb) = e;
  } else {
    int r = row - NS;
    const float* tb = tt + (size_t)tid[r]*DD + colb;
    float4 a0 = ((const float4*)tb)[0], a1 = ((const float4*)tb)[1];
    float4 b0 = ((const float4*)(bpar+colb))[0], b1 = ((const float4*)(bpar+colb))[1];
    a0.x += b0.x; a0.y += b0.y; a0.z += b0.z; a0.w += b0.w;
    a1.x += b1.x; a1.y += b1.y; a1.z += b1.z; a1.w += b1.w;
    const float* pr = pp + (size_t)r*8;
    float4 p0 = ((const float4*)pr)[0], p1 = ((const float4*)pr)[1];
    float w[8] = {p0.x,p0.y,p0.z,p0.w,p1.x,p1.y,p1.z,p1.w};
    #pragma unroll
    for (int p = 0; p < 8; p++){
      float4 w0 = ((const float4*)(Wpar + p*DD + colb))[0];
      float4 w1 = ((const float4*)(Wpar + p*DD + colb))[1];
      a0.x += w[p]*w0.x; a0.y += w[p]*w0.y; a0.z += w[p]*w0.z; a0.w += w[p]*w0.w;
      a1.x += w[p]*w1.x; a1.y += w[p]*w1.y; a1.z += w[p]*w1.z; a1.w += w[p]*w1.w;
    }
    u32x4 o;
    o.x = packbf(a0.x, a0.y); o.y = packbf(a0.z, a0.w);
    o.z = packbf(a1.x, a1.y); o.w = packbf(a1.z, a1.w);
    *(u32x4*)(hr + (size_t)r*DD + colb) = o;
  }
}

// ---------------- bucketed CSR build ----------------
__global__ __launch_bounds__(256) void bucket_hist(const int* __restrict__ er, const int* __restrict__ es,
                                                   int* __restrict__ gcnt){
  __shared__ int cnt[NBR + NBS];
  int t = threadIdx.x;
  for (int j = t; j < NBR + NBS; j += 256) cnt[j] = 0;
  __syncthreads();
  long i0 = (long)blockIdx.x * 2048;
  for (int j = t; j < 2048; j += 256){
    long i = i0 + j;
    if (i < EE){
      atomicAdd(&cnt[er[i] >> BSH], 1);
      atomicAdd(&cnt[NBR + (es[i] >> BSH)], 1);
    }
  }
  __syncthreads();
  for (int j = t; j < NBR + NBS; j += 256)
    if (cnt[j]) atomicAdd(&gcnt[j], cnt[j]);
}

__global__ __launch_bounds__(256) void bucket_scan(const int* __restrict__ gcnt,
        int* __restrict__ bktOffR, int* __restrict__ bktOffS,
        int* __restrict__ gCurR, int* __restrict__ gCurS){
  __shared__ int a[256];
  int t = threadIdx.x;
  int own = (t < NBR) ? gcnt[t] : 0;
  a[t] = own; __syncthreads();
  for (int d = 1; d < 256; d <<= 1){
    int x = (t >= d) ? a[t-d] : 0;
    __syncthreads(); a[t] += x; __syncthreads();
  }
  if (t < NBR){ int v = a[t] - own; bktOffR[t] = v; gCurR[t] = v; }
  if (t == 0) bktOffR[NBR] = EE;
  __syncthreads();
  own = (t < NBS) ? gcnt[NBR + t] : 0;
  a[t] = own; __syncthreads();
  for (int d = 1; d < 256; d <<= 1){
    int x = (t >= d) ? a[t-d] : 0;
    __syncthreads(); a[t] += x; __syncthreads();
  }
  if (t < NBS){ int v = a[t] - own; bktOffS[t] = v; gCurS[t] = v; }
  if (t == 0) bktOffS[NBS] = EE;
}

__global__ __launch_bounds__(256) void bin_edges(const int* __restrict__ er, const int* __restrict__ es,
        int* __restrict__ gCurR, int* __restrict__ gCurS,
        unsigned* __restrict__ recR, unsigned* __restrict__ recS){
  __shared__ unsigned stage[CHUNK];
  __shared__ unsigned char stageb[CHUNK];
  __shared__ int cnt[256], scn[256], pref[256], gbase[256], lcur[256];
  int t = threadIdx.x;
  int side = blockIdx.y;
  const int* dest = side ? es : er;
  const int* srca = side ? er : es;
  int* gCur = side ? gCurS : gCurR;
  unsigned* rec = side ? recS : recR;
  int nbkt = side ? NBS : NBR;
  long i0 = (long)blockIdx.x * CHUNK;
  int n = (EE - i0 < CHUNK) ? (int)(EE - i0) : CHUNK;
  cnt[t] = 0;
  __syncthreads();
  for (int j = t; j < n; j += 256)
    atomicAdd(&cnt[dest[i0 + j] >> BSH], 1);
  __syncthreads();
  scn[t] = cnt[t];
  __syncthreads();
  for (int d = 1; d < 256; d <<= 1){
    int x = (t >= d) ? scn[t-d] : 0;
    __syncthreads(); scn[t] += x; __syncthreads();
  }
  pref[t] = scn[t] - cnt[t];
  lcur[t] = scn[t] - cnt[t];
  if (t < nbkt && cnt[t] > 0) gbase[t] = atomicAdd(&gCur[t], cnt[t]);
  __syncthreads();
  for (int j = t; j < n; j += 256){
    int d = dest[i0 + j];
    int s = srca[i0 + j];
    int b = d >> BSH;
    int p = atomicAdd(&lcur[b], 1);
    stage[p] = ((unsigned)(d - (b << BSH)) << 18) | (unsigned)s;
    stageb[p] = (unsigned char)b;
  }
  __syncthreads();
  for (int e = t; e < n; e += 256){
    int b = stageb[e];
    rec[gbase[b] + (e - pref[b])] = stage[e];
  }
}

// Stage 4: scatter PRESCALED records: (dloc<<26) | (src*256)  [src byte offset]
__global__ __launch_bounds__(256) void build_csr(const unsigned* __restrict__ recR, const unsigned* __restrict__ recS,
        const int* __restrict__ bktOffR, const int* __restrict__ bktOffS,
        unsigned* __restrict__ csrR, unsigned* __restrict__ csrS,
        int* __restrict__ offsR, int* __restrict__ offsS){
  __shared__ int hist[1024], pref[1024], cur[1024], ws[256];
  int t = threadIdx.x;
  int bb = blockIdx.x;
  const unsigned* rec; const int* bktOff; unsigned* csr; int* offs; int N;
  if (bb < NBR){ rec = recR; bktOff = bktOffR; csr = csrR; offs = offsR; N = NR; }
  else { bb -= NBR; rec = recS; bktOff = bktOffS; csr = csrS; offs = offsS; N = NS; }
  int d0 = bb << BSH;
  int base = bktOff[bb], cnt_ = bktOff[bb+1] - base;
  #pragma unroll
  for (int j = 0; j < 4; j++) hist[t*4+j] = 0;
  __syncthreads();
  for (int e = t; e < cnt_; e += 256)
    atomicAdd(&hist[rec[base + e] >> 18], 1);
  __syncthreads();
  int s = 0, h[4];
  #pragma unroll
  for (int j = 0; j < 4; j++){ h[j] = hist[t*4+j]; s += h[j]; }
  ws[t] = s;
  __syncthreads();
  for (int d = 1; d < 256; d <<= 1){
    int x = (t >= d) ? ws[t-d] : 0;
    __syncthreads(); ws[t] += x; __syncthreads();
  }
  int run = ws[t] - s;
  #pragma unroll
  for (int j = 0; j < 4; j++){ pref[t*4+j] = run; cur[t*4+j] = base + run; run += h[j]; }
  __syncthreads();
  int DPB = N - d0; if (DPB > 1024) DPB = 1024;
  #pragma unroll
  for (int j = 0; j < 4; j++){
    int i = t*4 + j;
    if (i < DPB) offs[d0 + i] = base + pref[i];
  }
  if (t == 0 && d0 + DPB == N) offs[N] = EE;
  __syncthreads();
  for (int e = t; e < cnt_; e += 256){
    unsigned r = rec[base + e];
    int pos = atomicAdd(&cur[r >> 18], 1);
    csr[pos] = (((r >> 18) & 31u) << 26) | ((r & 0x3FFFFu) << 8);  // dloc<<26 | src byte-offset
  }
}

// ============ fused streaming-gather + concat-GEMM + bias + relu ============
// R7: batched wide gather WITH memory-level parallelism. R6's regression was
// the serial chain {csr load -> addr -> dwordx4 -> accumulate} per batch
// (~1 load in flight/wave). Records are CONTIGUOUS csr[k..ke) -> independent
// of data. New loop: 2 rows x 2 batches per pass = 4 record loads issued
// together, then 4 dwordx4 each gated only on its own record (per-register
// vmcnt) -> 4-8 loads in flight steady. One pass covers deg<=16 (Poisson
// mean 5/10); rare tail loops. Tree-reduce + swizzled msgT write verbatim
// from R6 (correctness-proven).
__global__ __launch_bounds__(256) void fused_layer(
        const unsigned char*  __restrict__ gsrc8,  // gather source rows (fp8 e4m3)
        const unsigned short* __restrict__ hself,  // self features (bf16)
        const int* __restrict__ offs, const unsigned* __restrict__ csr,
        const unsigned short* __restrict__ Wp, const float* __restrict__ bias,
        unsigned short* __restrict__ hout,         // bf16 out
        unsigned char*  __restrict__ hout8)        // fp8 shadow out (may be null)
{
  __shared__ unsigned short msgT[32*DD];   // 8 KB; 16B chunks swizzled: slot = c ^ (row&7)
  int t = threadIdx.x;
  int lane = t & 63;
  int w = t >> 6;
  int quad = lane >> 4, rlo = lane & 15;
  int row0 = blockIdx.x * 32;

  // ---- phase 1: 2 rows in flight, 2 batches/row/pass (8 edges per dwordx4) ----
  {
    int g = lane >> 3;          // edge slot within batch (0..7)
    int s = lane & 7;           // column chunk: cols s*16 .. s*16+15
    const unsigned char* g8 = gsrc8;
    int rbeg = row0 + w*8;
    int off_[9];
    #pragma unroll
    for (int i = 0; i < 9; i++) off_[i] = __builtin_amdgcn_readfirstlane(offs[rbeg + i]);

    #pragma unroll 1
    for (int rp = 0; rp < 4; rp++){
      int kA = off_[2*rp],   keA = off_[2*rp+1];
      int kB = off_[2*rp+1], keB = off_[2*rp+2];
      f32x2 A[8], B[8];
      #pragma unroll
      for (int i = 0; i < 8; i++){ f32x2 z = {0.f,0.f}; A[i] = z; B[i] = z; }

      while (true){
        // record loads: contiguous csr, no dependencies -> all issue together
        int iA0 = kA + g;     if (iA0 > keA-1) iA0 = keA-1; if (iA0 < 0) iA0 = 0;
        int iA1 = kA + 8 + g; if (iA1 > keA-1) iA1 = keA-1; if (iA1 < 0) iA1 = 0;
        int iB0 = kB + g;     if (iB0 > keB-1) iB0 = keB-1; if (iB0 < 0) iB0 = 0;
        int iB1 = kB + 8 + g; if (iB1 > keB-1) iB1 = keB-1; if (iB1 < 0) iB1 = 0;
        unsigned rA0 = csr[iA0], rA1 = csr[iA1];
        unsigned rB0 = csr[iB0], rB1 = csr[iB1];
        // data loads: each waits only its own record (per-register vmcnt)
        u32x4 dA0 = *(const u32x4*)(g8 + ((rA0 & 0x03FFFF00u) >> 1) + s*16);
        u32x4 dA1 = *(const u32x4*)(g8 + ((rA1 & 0x03FFFF00u) >> 1) + s*16);
        u32x4 dB0 = *(const u32x4*)(g8 + ((rB0 & 0x03FFFF00u) >> 1) + s*16);
        u32x4 dB1 = *(const u32x4*)(g8 + ((rB1 & 0x03FFFF00u) >> 1) + s*16);
        // masks (fp8 0x00 == 0.0f)
        unsigned mA0 = (kA + g     < keA) ? 0xFFFFFFFFu : 0u;
        unsigned mA1 = (kA + 8 + g < keA) ? 0xFFFFFFFFu : 0u;
        unsigned mB0 = (kB + g     < keB) ? 0xFFFFFFFFu : 0u;
        unsigned mB1 = (kB + 8 + g < keB) ? 0xFFFFFFFFu : 0u;
        dA0.x &= mA0; dA0.y &= mA0; dA0.z &= mA0; dA0.w &= mA0;
        dA1.x &= mA1; dA1.y &= mA1; dA1.z &= mA1; dA1.w &= mA1;
        dB0.x &= mB0; dB0.y &= mB0; dB0.z &= mB0; dB0.w &= mB0;
        dB1.x &= mB1; dB1.y &= mB1; dB1.z &= mB1; dB1.w &= mB1;
        ACC8(A, dA0); ACC8(A, dA1);
        ACC8(B, dB0); ACC8(B, dB1);
        kA += 16; kB += 16;
        if (kA >= keA && kB >= keB) break;   // uniform scalar condition
      }

      // 3-level cross-group tree: fold the 8 edge-groups (xor 8/16/32)
      #pragma unroll
      for (int msk = 8; msk <= 32; msk <<= 1){
        #pragma unroll
        for (int i = 0; i < 8; i++){
          A[i][0] += __shfl_xor(A[i][0], msk, 64);
          A[i][1] += __shfl_xor(A[i][1], msk, 64);
          B[i][0] += __shfl_xor(B[i][0], msk, 64);
          B[i][1] += __shfl_xor(B[i][1], msk, 64);
        }
      }
      // groups 0,1 hold full sums; write swizzled 16B chunks (2s+g)^(row&7)
      if (g < 2){
        u32x4 oA, oB;
        if (g == 0){
          oA.x = packbf(A[0][0],A[0][1]); oA.y = packbf(A[1][0],A[1][1]);
          oA.z = packbf(A[2][0],A[2][1]); oA.w = packbf(A[3][0],A[3][1]);
          oB.x = packbf(B[0][0],B[0][1]); oB.y = packbf(B[1][0],B[1][1]);
          oB.z = packbf(B[2][0],B[2][1]); oB.w = packbf(B[3][0],B[3][1]);
        } else {
          oA.x = packbf(A[4][0],A[4][1]); oA.y = packbf(A[5][0],A[5][1]);
          oA.z = packbf(A[6][0],A[6][1]); oA.w = packbf(A[7][0],A[7][1]);
          oB.x = packbf(B[4][0],B[4][1]); oB.y = packbf(B[5][0],B[5][1]);
          oB.z = packbf(B[6][0],B[6][1]); oB.w = packbf(B[7][0],B[7][1]);
        }
        int lrA = w*8 + 2*rp, lrB = lrA + 1;
        int cA = (2*s + g) ^ (lrA & 7);
        int cB = (2*s + g) ^ (lrB & 7);
        *(u32x4*)(msgT + (size_t)lrA*DD + cA*8) = oA;
        *(u32x4*)(msgT + (size_t)lrB*DD + cB*8) = oB;
      }
    }
  }
  __syncthreads();

  // ---- phase 2: MFMA. W = A-operand, H/msg = B-operand. Wave -> 32-col strip. ----
  int ct0 = w * 2;
  bf16x8 wf[16];                         // [ks][c]
  #pragma unroll
  for (int ks = 0; ks < 8; ks++){
    wf[ks*2+0] = *(const bf16x8*)(Wp + (size_t)(((ct0+0)*8 + ks)*64 + lane) * 8);
    wf[ks*2+1] = *(const bf16x8*)(Wp + (size_t)(((ct0+1)*8 + ks)*64 + lane) * 8);
  }
  bf16x8 Hb0[4], Hb1[4];
  #pragma unroll
  for (int ks = 0; ks < 4; ks++){
    int kloc = ks*32 + quad*8;
    Hb0[ks] = *(const bf16x8*)(hself + (size_t)(row0 + rlo) * DD + kloc);
    Hb1[ks] = *(const bf16x8*)(hself + (size_t)(row0 + 16 + rlo) * DD + kloc);
  }
  bf16x8 Mb0[4], Mb1[4];
  #pragma unroll
  for (int ks2 = 0; ks2 < 4; ks2++){
    int c8 = ks2*4 + quad;               // 16B chunk index 0..15
    int lr0 = rlo, lr1 = 16 + rlo;
    Mb0[ks2] = *(const bf16x8*)(msgT + lr0*DD + ((c8 ^ (lr0 & 7)) * 8));
    Mb1[ks2] = *(const bf16x8*)(msgT + lr1*DD + ((c8 ^ (lr1 & 7)) * 8));
  }

  f32x4 acc[2][2];
  #pragma unroll
  for (int i = 0; i < 2; i++)
    #pragma unroll
    for (int j = 0; j < 2; j++){ f32x4 z = {0.f,0.f,0.f,0.f}; acc[i][j] = z; }

  #pragma unroll
  for (int ks = 0; ks < 4; ks++){
    acc[0][0] = __builtin_amdgcn_mfma_f32_16x16x32_bf16(wf[ks*2+0], Hb0[ks], acc[0][0], 0, 0, 0);
    acc[0][1] = __builtin_amdgcn_mfma_f32_16x16x32_bf16(wf[ks*2+1], Hb0[ks], acc[0][1], 0, 0, 0);
    acc[1][0] = __builtin_amdgcn_mfma_f32_16x16x32_bf16(wf[ks*2+0], Hb1[ks], acc[1][0], 0, 0, 0);
    acc[1][1] = __builtin_amdgcn_mfma_f32_16x16x32_bf16(wf[ks*2+1], Hb1[ks], acc[1][1], 0, 0, 0);
  }
  #pragma unroll
  for (int ks2 = 0; ks2 < 4; ks2++){
    int ks = 4 + ks2;
    acc[0][0] = __builtin_amdgcn_mfma_f32_16x16x32_bf16(wf[ks*2+0], Mb0[ks2], acc[0][0], 0, 0, 0);
    acc[0][1] = __builtin_amdgcn_mfma_f32_16x16x32_bf16(wf[ks*2+1], Mb0[ks2], acc[0][1], 0, 0, 0);
    acc[1][0] = __builtin_amdgcn_mfma_f32_16x16x32_bf16(wf[ks*2+0], Mb1[ks2], acc[1][0], 0, 0, 0);
    acc[1][1] = __builtin_amdgcn_mfma_f32_16x16x32_bf16(wf[ks*2+1], Mb1[ks2], acc[1][1], 0, 0, 0);
  }

  // epilogue: acc[rb][c][i] = out[row0+rb*16+rlo][(ct0+c)*16 + quad*4 + i]
  #pragma unroll
  for (int c = 0; c < 2; c++){
    float4 bv = *(const float4*)(bias + (ct0+c)*16 + quad*4);
    #pragma unroll
    for (int rb = 0; rb < 2; rb++){
      int row = row0 + rb*16 + rlo;
      float v0 = acc[rb][c][0] + bv.x;
      float v1 = acc[rb][c][1] + bv.y;
      float v2 = acc[rb][c][2] + bv.z;
      float v3 = acc[rb][c][3] + bv.w;
      v0 = v0 > 0.f ? v0 : 0.f;
      v1 = v1 > 0.f ? v1 : 0.f;
      v2 = v2 > 0.f ? v2 : 0.f;
      v3 = v3 > 0.f ? v3 : 0.f;
      u32x2 o; o.x = packbf(v0, v1); o.y = packbf(v2, v3);
      *(u32x2*)(hout + (size_t)row*DD + (ct0+c)*16 + quad*4) = o;
      if (hout8)
        *(unsigned*)(hout8 + (size_t)row*DD + (ct0+c)*16 + quad*4) = pack4fp8(v0, v1, v2, v3);
    }
  }
}

// ---------------- segment-mean pooling: 16B loads, 2-stage reduce ----------------
__global__ __launch_bounds__(256) void pool(const unsigned short* __restrict__ hs,
        const unsigned short* __restrict__ hr, float* __restrict__ out){
  __shared__ float red[16][128];
  int b = blockIdx.x, part = blockIdx.y;   // part<4: species, else reactions (500 rows each)
  int t = threadIdx.x;
  int rg = t >> 4, sub = t & 15;
  const unsigned short* src; int row0, outoff; float scale;
  if (part < 4){ src = hs; row0 = b*NSP + part*500; outoff = b*256; scale = 1.f/NSP; }
  else { src = hr; row0 = b*NRP + (part-4)*500; outoff = b*256 + 128; scale = 1.f/NRP; }
  float a0=0,a1=0,a2=0,a3=0,a4=0,a5=0,a6=0,a7=0;
  for (int r = rg; r < 500; r += 16){
    u32x4 p = *(const u32x4*)(src + (size_t)(row0+r)*DD + sub*8);
    a0 += bflo(p.x); a1 += bfhi(p.x);
    a2 += bflo(p.y); a3 += bfhi(p.y);
    a4 += bflo(p.z); a5 += bfhi(p.z);
    a6 += bflo(p.w); a7 += bfhi(p.w);
  }
  float* rr = &red[rg][sub*8];
  rr[0]=a0; rr[1]=a1; rr[2]=a2; rr[3]=a3; rr[4]=a4; rr[5]=a5; rr[6]=a6; rr[7]=a7;
  __syncthreads();
  if (t < 128){
    float s = 0.f;
    #pragma unroll
    for (int g = 0; g < 16; g++) s += red[g][t];
    atomicAdd(&out[outoff + t], s * scale);
  }
}

extern "C" void kernel_launch(void* const* d_in, const int* in_sizes, int n_in,
                              void* d_out, int out_size, void* d_ws, size_t ws_size,
                              hipStream_t stream)
{
  const int*   si   = (const int*)d_in[0];
  const int*   ext  = (const int*)d_in[1];
  const int*   tid  = (const int*)d_in[2];
  const float* pp   = (const float*)d_in[3];
  const int*   es   = (const int*)d_in[4];
  const int*   er   = (const int*)d_in[5];
  const float* st   = (const float*)d_in[8];
  const float* et   = (const float*)d_in[9];
  const float* tt   = (const float*)d_in[10];
  const float* Wpar = (const float*)d_in[11];
  const float* bpar = (const float*)d_in[12];
  const float* Wr   = (const float*)d_in[13];
  const float* br   = (const float*)d_in[14];
  const float* Ws   = (const float*)d_in[15];
  const float* bs   = (const float*)d_in[16];
  float* out = (float*)d_out;

  char* basep = (char*)d_ws; size_t off = 0;
  auto alloc = [&](size_t bytes)->char*{
    char* r = basep + off; off = (off + bytes + 255) & ~(size_t)255; return r;
  };
  unsigned short* hs0 = (unsigned short*)alloc((size_t)NS*DD*2);
  unsigned short* hs1 = (unsigned short*)alloc((size_t)NS*DD*2);
  unsigned short* hr0 = (unsigned short*)alloc((size_t)NR*DD*2);
  unsigned short* hr1 = (unsigned short*)alloc((size_t)NR*DD*2);
  unsigned short* Wp  = (unsigned short*)alloc((size_t)4*32768*2);
  int* offsR = (int*)alloc((size_t)(NR+1)*4);
  int* offsS = (int*)alloc((size_t)(NS+1)*4);
  unsigned* csrR = (unsigned*)alloc((size_t)EE*4);
  unsigned* csrS = (unsigned*)alloc((size_t)EE*4);
  // fp8 shadow buffers (live ranges alternate, 2 suffice):
  //   f8S: hs shadow (written by init / S-side layers), f8R: hr shadow
  unsigned char* f8S = (unsigned char*)alloc((size_t)NS*DD);
  unsigned char* f8R = (unsigned char*)alloc((size_t)NR*DD);
  int* gcnt   = (int*)alloc(2048);
  int* bktOffR= (int*)alloc(2048);
  int* bktOffS= (int*)alloc(2048);
  int* gCurR  = (int*)alloc(2048);
  int* gCurS  = (int*)alloc(2048);
  // rec arrays only live during CSR build; alias into the ping buffers
  // (hs1 / hr1 are first written at layer-0 fused dispatches, after build_csr).
  unsigned* recR = (unsigned*)hs1;            // 4 MB within 25.6 MB
  unsigned* recS = (unsigned*)hr1;            // 4 MB within 51.2 MB

  hipMemsetAsync(gcnt, 0, 2048, stream);
  hipMemsetAsync(d_out, 0, (size_t)out_size*4, stream);

  pack_w<<<512, 256, 0, stream>>>(Wr, Ws, Wp);
  init_all<<<(NS+NR)*16/256, 256, 0, stream>>>(si, ext, tid, pp, st, et, tt, Wpar, bpar, hs0, hr0, f8S);

  bucket_hist<<<(EE + 2047)/2048, 256, 0, stream>>>(er, es, gcnt);
  bucket_scan<<<1, 256, 0, stream>>>(gcnt, bktOffR, bktOffS, gCurR, gCurS);
  bin_edges<<<dim3((EE + CHUNK - 1)/CHUNK, 2), 256, 0, stream>>>(er, es, gCurR, gCurS, recR, recS);
  build_csr<<<NBR + NBS, 256, 0, stream>>>(recR, recS, bktOffR, bktOffS, csrR, csrS, offsR, offsS);

  // layer 0
  fused_layer<<<NR/32, 256, 0, stream>>>(f8S, hr0, offsR, csrR, Wp + (size_t)0*32768, br + (size_t)0*DD, hr1, f8R);
  fused_layer<<<NS/32, 256, 0, stream>>>(f8R, hs0, offsS, csrS, Wp + (size_t)2*32768, bs + (size_t)0*DD, hs1, f8S);
  // layer 1
  fused_layer<<<NR/32, 256, 0, stream>>>(f8S, hr1, offsR, csrR, Wp + (size_t)1*32768, br + (size_t)1*DD, hr0, f8R);
  fused_layer<<<NS/32, 256, 0, stream>>>(f8R, hs1, offsS, csrS, Wp + (size_t)3*32768, bs + (size_t)1*DD, hs0, (unsigned char*)nullptr);

  pool<<<dim3(NB, 12), 256, 0, stream>>>(hs0, hr0, out);
}

// Round 8
// 477.413 us; speedup vs baseline: 1.3426x; 1.3426x over previous
//
#include <hip/hip_runtime.h>
#include <stdint.h>

#define NS 100000
#define NR 200000
#define EE 1000000
#define DD 128
#define NB 50
#define NSP 2000
#define NRP 4000
#define BSH 10
#define NBR 196   /* ceil(NR/1024) */
#define NBS 98    /* ceil(NS/1024) */
#define CHUNK 8192

typedef short bf16x8 __attribute__((ext_vector_type(8)));
typedef float f32x4 __attribute__((ext_vector_type(4)));
typedef unsigned u32x4 __attribute__((ext_vector_type(4)));
typedef unsigned u32x2 __attribute__((ext_vector_type(2)));

__device__ __forceinline__ unsigned short f2bf(float f){
  unsigned u = __float_as_uint(f);
  u = (u + 0x7FFFu + ((u >> 16) & 1u)) >> 16;
  return (unsigned short)u;
}
__device__ __forceinline__ unsigned packbf(float a, float b){
  return (unsigned)f2bf(a) | ((unsigned)f2bf(b) << 16);
}
__device__ __forceinline__ float bflo(unsigned p){ return __uint_as_float(p << 16); }
__device__ __forceinline__ float bfhi(unsigned p){ return __uint_as_float(p & 0xFFFF0000u); }

// ---------------- weight pre-pack into MFMA fragment order ----------------
// Wp[mat][ct][ks][lane][j] = W[mat][k = ks*32 + (lane>>4)*8 + j][col = ct*16 + (lane&15)]
__global__ void pack_w(const float* __restrict__ Wr, const float* __restrict__ Ws,
                       unsigned short* __restrict__ Wp){
  int g = blockIdx.x*256 + threadIdx.x;   // 4*32768 = 131072 total
  if (g >= 4*32768) return;
  int j = g & 7; int rest = g >> 3;
  int lane = rest & 63; rest >>= 6;
  int ks = rest & 7; rest >>= 3;
  int ct = rest & 7; int mat = rest >> 3;
  int k  = ks*32 + (lane >> 4)*8 + j;
  int cc = ct*16 + (lane & 15);
  const float* src = (mat < 2) ? (Wr + (size_t)mat*256*DD) : (Ws + (size_t)(mat-2)*256*DD);
  Wp[g] = f2bf(src[(size_t)k*DD + cc]);
}

// ---------------- fused embedding init: 16B stores, float4 reads ----------------
__global__ __launch_bounds__(256) void init_all(const int* __restrict__ si, const int* __restrict__ ext,
        const int* __restrict__ tid, const float* __restrict__ pp,
        const float* __restrict__ st, const float* __restrict__ et, const float* __restrict__ tt,
        const float* __restrict__ Wpar, const float* __restrict__ bpar,
        unsigned short* __restrict__ hs, unsigned short* __restrict__ hr){
  int g = blockIdx.x*256 + threadIdx.x;   // (NS+NR)*16 total
  int row = g >> 4, colb = (g & 15) * 8;
  if (row < NS){
    const float* a = st + (size_t)si[row]*DD + colb;
    const float* b = et + (size_t)ext[row]*DD + colb;
    float4 x0 = ((const float4*)a)[0], x1 = ((const float4*)a)[1];
    float4 y0 = ((const float4*)b)[0], y1 = ((const float4*)b)[1];
    u32x4 o;
    o.x = packbf(x0.x+y0.x, x0.y+y0.y);
    o.y = packbf(x0.z+y0.z, x0.w+y0.w);
    o.z = packbf(x1.x+y1.x, x1.y+y1.y);
    o.w = packbf(x1.z+y1.z, x1.w+y1.w);
    *(u32x4*)(hs + (size_t)row*DD + colb) = o;
  } else {
    int r = row - NS;
    const float* tb = tt + (size_t)tid[r]*DD + colb;
    float4 a0 = ((const float4*)tb)[0], a1 = ((const float4*)tb)[1];
    float4 b0 = ((const float4*)(bpar+colb))[0], b1 = ((const float4*)(bpar+colb))[1];
    a0.x += b0.x; a0.y += b0.y; a0.z += b0.z; a0.w += b0.w;
    a1.x += b1.x; a1.y += b1.y; a1.z += b1.z; a1.w += b1.w;
    const float* pr = pp + (size_t)r*8;
    float4 p0 = ((const float4*)pr)[0], p1 = ((const float4*)pr)[1];
    float w[8] = {p0.x,p0.y,p0.z,p0.w,p1.x,p1.y,p1.z,p1.w};
    #pragma unroll
    for (int p = 0; p < 8; p++){
      float4 w0 = ((const float4*)(Wpar + p*DD + colb))[0];
      float4 w1 = ((const float4*)(Wpar + p*DD + colb))[1];
      a0.x += w[p]*w0.x; a0.y += w[p]*w0.y; a0.z += w[p]*w0.z; a0.w += w[p]*w0.w;
      a1.x += w[p]*w1.x; a1.y += w[p]*w1.y; a1.z += w[p]*w1.z; a1.w += w[p]*w1.w;
    }
    u32x4 o;
    o.x = packbf(a0.x, a0.y); o.y = packbf(a0.z, a0.w);
    o.z = packbf(a1.x, a1.y); o.w = packbf(a1.z, a1.w);
    *(u32x4*)(hr + (size_t)r*DD + colb) = o;
  }
}

// ---------------- bucketed CSR build ----------------
__global__ __launch_bounds__(256) void bucket_hist(const int* __restrict__ er, const int* __restrict__ es,
                                                   int* __restrict__ gcnt){
  __shared__ int cnt[NBR + NBS];
  int t = threadIdx.x;
  for (int j = t; j < NBR + NBS; j += 256) cnt[j] = 0;
  __syncthreads();
  long i0 = (long)blockIdx.x * 2048;
  for (int j = t; j < 2048; j += 256){
    long i = i0 + j;
    if (i < EE){
      atomicAdd(&cnt[er[i] >> BSH], 1);
      atomicAdd(&cnt[NBR + (es[i] >> BSH)], 1);
    }
  }
  __syncthreads();
  for (int j = t; j < NBR + NBS; j += 256)
    if (cnt[j]) atomicAdd(&gcnt[j], cnt[j]);
}

__global__ __launch_bounds__(256) void bucket_scan(const int* __restrict__ gcnt,
        int* __restrict__ bktOffR, int* __restrict__ bktOffS,
        int* __restrict__ gCurR, int* __restrict__ gCurS){
  __shared__ int a[256];
  int t = threadIdx.x;
  int own = (t < NBR) ? gcnt[t] : 0;
  a[t] = own; __syncthreads();
  for (int d = 1; d < 256; d <<= 1){
    int x = (t >= d) ? a[t-d] : 0;
    __syncthreads(); a[t] += x; __syncthreads();
  }
  if (t < NBR){ int v = a[t] - own; bktOffR[t] = v; gCurR[t] = v; }
  if (t == 0) bktOffR[NBR] = EE;
  __syncthreads();
  own = (t < NBS) ? gcnt[NBR + t] : 0;
  a[t] = own; __syncthreads();
  for (int d = 1; d < 256; d <<= 1){
    int x = (t >= d) ? a[t-d] : 0;
    __syncthreads(); a[t] += x; __syncthreads();
  }
  if (t < NBS){ int v = a[t] - own; bktOffS[t] = v; gCurS[t] = v; }
  if (t == 0) bktOffS[NBS] = EE;
}

__global__ __launch_bounds__(256) void bin_edges(const int* __restrict__ er, const int* __restrict__ es,
        int* __restrict__ gCurR, int* __restrict__ gCurS,
        unsigned* __restrict__ recR, unsigned* __restrict__ recS){
  __shared__ unsigned stage[CHUNK];
  __shared__ unsigned char stageb[CHUNK];
  __shared__ int cnt[256], scn[256], pref[256], gbase[256], lcur[256];
  int t = threadIdx.x;
  int side = blockIdx.y;
  const int* dest = side ? es : er;
  const int* srca = side ? er : es;
  int* gCur = side ? gCurS : gCurR;
  unsigned* rec = side ? recS : recR;
  int nbkt = side ? NBS : NBR;
  long i0 = (long)blockIdx.x * CHUNK;
  int n = (EE - i0 < CHUNK) ? (int)(EE - i0) : CHUNK;
  cnt[t] = 0;
  __syncthreads();
  for (int j = t; j < n; j += 256)
    atomicAdd(&cnt[dest[i0 + j] >> BSH], 1);
  __syncthreads();
  scn[t] = cnt[t];
  __syncthreads();
  for (int d = 1; d < 256; d <<= 1){
    int x = (t >= d) ? scn[t-d] : 0;
    __syncthreads(); scn[t] += x; __syncthreads();
  }
  pref[t] = scn[t] - cnt[t];
  lcur[t] = scn[t] - cnt[t];
  if (t < nbkt && cnt[t] > 0) gbase[t] = atomicAdd(&gCur[t], cnt[t]);
  __syncthreads();
  for (int j = t; j < n; j += 256){
    int d = dest[i0 + j];
    int s = srca[i0 + j];
    int b = d >> BSH;
    int p = atomicAdd(&lcur[b], 1);
    stage[p] = ((unsigned)(d - (b << BSH)) << 18) | (unsigned)s;
    stageb[p] = (unsigned char)b;
  }
  __syncthreads();
  for (int e = t; e < n; e += 256){
    int b = stageb[e];
    rec[gbase[b] + (e - pref[b])] = stage[e];
  }
}

// Stage 4: scatter PRESCALED records: (dloc<<26) | (src*256)  [src byte offset]
__global__ __launch_bounds__(256) void build_csr(const unsigned* __restrict__ recR, const unsigned* __restrict__ recS,
        const int* __restrict__ bktOffR, const int* __restrict__ bktOffS,
        unsigned* __restrict__ csrR, unsigned* __restrict__ csrS,
        int* __restrict__ offsR, int* __restrict__ offsS){
  __shared__ int hist[1024], pref[1024], cur[1024], ws[256];
  int t = threadIdx.x;
  int bb = blockIdx.x;
  const unsigned* rec; const int* bktOff; unsigned* csr; int* offs; int N;
  if (bb < NBR){ rec = recR; bktOff = bktOffR; csr = csrR; offs = offsR; N = NR; }
  else { bb -= NBR; rec = recS; bktOff = bktOffS; csr = csrS; offs = offsS; N = NS; }
  int d0 = bb << BSH;
  int base = bktOff[bb], cnt_ = bktOff[bb+1] - base;
  #pragma unroll
  for (int j = 0; j < 4; j++) hist[t*4+j] = 0;
  __syncthreads();
  for (int e = t; e < cnt_; e += 256)
    atomicAdd(&hist[rec[base + e] >> 18], 1);
  __syncthreads();
  int s = 0, h[4];
  #pragma unroll
  for (int j = 0; j < 4; j++){ h[j] = hist[t*4+j]; s += h[j]; }
  ws[t] = s;
  __syncthreads();
  for (int d = 1; d < 256; d <<= 1){
    int x = (t >= d) ? ws[t-d] : 0;
    __syncthreads(); ws[t] += x; __syncthreads();
  }
  int run = ws[t] - s;
  #pragma unroll
  for (int j = 0; j < 4; j++){ pref[t*4+j] = run; cur[t*4+j] = base + run; run += h[j]; }
  __syncthreads();
  int DPB = N - d0; if (DPB > 1024) DPB = 1024;
  #pragma unroll
  for (int j = 0; j < 4; j++){
    int i = t*4 + j;
    if (i < DPB) offs[d0 + i] = base + pref[i];
  }
  if (t == 0 && d0 + DPB == N) offs[N] = EE;
  __syncthreads();
  for (int e = t; e < cnt_; e += 256){
    unsigned r = rec[base + e];
    int pos = atomicAdd(&cur[r >> 18], 1);
    csr[pos] = (((r >> 18) & 31u) << 26) | ((r & 0x3FFFFu) << 8);  // dloc<<26 | src byte-offset
  }
}

// ============ fused streaming-gather + concat-GEMM + bias + relu ============
// R8: dense DUAL-EDGE gather on the R0 skeleton. Ledger (R0/R3/R5/R6/R7):
// per-edge cost tracks vmem INSTRUCTIONS (~44cy/instr/CU at full occupancy),
// independent of bytes. So: one dwordx2 instruction fetches TWO bf16 source
// rows (lower 32 lanes = edge 2j, upper 32 = edge 2j+1; 8B/lane), densely in
// CSR order -> ~0.55 instr/edge. Per-lane 4 f32 partials (cols 4*(lane&31));
// row flush = 4x shfl_xor(32) fold + 8B swizzled msgT store from lanes<32;
// straddling pairs handled with half-masks on already-loaded data (bf16
// 0x0000 == 0). 3-bank record/data prefetch identical to R0. fp8 reverted.
__global__ __launch_bounds__(256) void fused_layer(
        const unsigned short* __restrict__ gsrc,   // gather source rows (bf16)
        const unsigned short* __restrict__ hself,  // self features (bf16)
        const int* __restrict__ offs, const unsigned* __restrict__ csr,
        const unsigned short* __restrict__ Wp, const float* __restrict__ bias,
        unsigned short* __restrict__ hout)
{
  __shared__ unsigned short msgT[32*DD];   // 8 KB; 16B chunks swizzled: slot = c16 ^ (row&7)
  int t = threadIdx.x;
  int lane = t & 63;
  int w = t >> 6;
  int quad = lane >> 4, rlo = lane & 15;
  int row0 = blockIdx.x * 32;

  // zero-init msg tile wave-exclusively (each wave owns rows w*8..w*8+7)
  {
    u32x4 z4 = {0u,0u,0u,0u};
    ((u32x4*)msgT)[w*128 + lane]      = z4;
    ((u32x4*)msgT)[w*128 + 64 + lane] = z4;
  }

  // ---- phase 1: dual-edge streaming (scalar control, 2 edges per dwordx2) ----
  {
    int rbeg = row0 + w*8;
    int kp = __builtin_amdgcn_readfirstlane(offs[rbeg]);
    int ke = __builtin_amdgcn_readfirstlane(offs[rbeg + 8]);
    int half = lane >> 5;         // 0: edge 2j, 1: edge 2j+1
    int col4 = lane & 31;         // cols 4*col4 .. 4*col4+3 (byte offset col4*8)
    const char* gbase = (const char*)gsrc;
    float a0 = 0.f, a1 = 0.f, a2 = 0.f, a3 = 0.f;
    int cur = -1;

    auto flushrow = [&](){
      float s0 = a0 + __shfl_xor(a0, 32, 64);
      float s1 = a1 + __shfl_xor(a1, 32, 64);
      float s2 = a2 + __shfl_xor(a2, 32, 64);
      float s3 = a3 + __shfl_xor(a3, 32, 64);
      if (lane < 32){
        u32x2 o; o.x = packbf(s0, s1); o.y = packbf(s2, s3);
        *(u32x2*)(msgT + cur*DD + (((col4 >> 1) ^ (cur & 7)) * 8) + ((col4 & 1) * 4)) = o;
      }
      a0 = 0.f; a1 = 0.f; a2 = 0.f; a3 = 0.f;
    };

    if (kp < ke){
      unsigned ra[8], rb[8], rcx[8];   // record banks (SGPR via readfirstlane)
      u32x2 pa[4], pb[4], pc[4];       // data banks: 4 dual-row dwordx2 each

      auto fetchrec = [&](unsigned* R, int kb){
        #pragma unroll
        for (int i = 0; i < 8; i++){
          int kk = kb + i; if (kk > ke-1) kk = ke-1;
          R[i] = (unsigned)__builtin_amdgcn_readfirstlane(csr[kk]);
        }
      };
      auto issue = [&](const unsigned* R, u32x2* P){
        #pragma unroll
        for (int j = 0; j < 4; j++){
          unsigned rsel = half ? R[2*j+1] : R[2*j];
          P[j] = *(const u32x2*)(gbase + (rsel & 0x03FFFF00u) + col4*8);
        }
      };
      auto process = [&](const unsigned* R, const u32x2* P, int kb){
        #pragma unroll
        for (int j = 0; j < 4; j++){
          if (kb + 2*j < ke){                         // scalar
            int dl0 = (int)(R[2*j]   >> 26);          // scalar
            int dl1 = (int)(R[2*j+1] >> 26);          // scalar
            bool v1 = (kb + 2*j + 1 < ke);            // scalar
            u32x2 d = P[j];
            if (dl0 != cur){ if (cur >= 0) flushrow(); cur = dl0; }
            if (v1 && dl1 == dl0){
              a0 += bflo(d.x); a1 += bfhi(d.x);
              a2 += bflo(d.y); a3 += bfhi(d.y);
            } else {
              unsigned mU = half ? 0u : 0xFFFFFFFFu;  // keep lower (edge 2j)
              unsigned x = d.x & mU, y = d.y & mU;
              a0 += bflo(x); a1 += bfhi(x);
              a2 += bflo(y); a3 += bfhi(y);
              if (v1){                                 // straddle: edge 2j+1 -> new row
                flushrow(); cur = dl1;
                unsigned mL = half ? 0xFFFFFFFFu : 0u; // keep upper (edge 2j+1)
                x = d.x & mL; y = d.y & mL;
                a0 += bflo(x); a1 += bfhi(x);
                a2 += bflo(y); a3 += bfhi(y);
              }
            }
          }
        }
      };

      // prologue: records for batches 0,1,2; data for batches 0,1
      fetchrec(ra, kp); fetchrec(rb, kp + 8); fetchrec(rcx, kp + 16);
      issue(ra, pa); issue(rb, pb);

      int k = kp;
      while (true){
        if (k >= ke) break;
        issue(rcx, pc);
        process(ra, pa, k);
        fetchrec(ra, k + 24);
        k += 8;

        if (k >= ke) break;
        issue(ra, pa);
        process(rb, pb, k);
        fetchrec(rb, k + 24);
        k += 8;

        if (k >= ke) break;
        issue(rb, pb);
        process(rcx, pc, k);
        fetchrec(rcx, k + 24);
        k += 8;
      }
      if (cur >= 0) flushrow();
    }
  }
  __syncthreads();

  // ---- phase 2: MFMA. W = A-operand, H/msg = B-operand. Wave -> 32-col strip. ----
  int ct0 = w * 2;
  bf16x8 wf[16];                         // [ks][c]
  #pragma unroll
  for (int ks = 0; ks < 8; ks++){
    wf[ks*2+0] = *(const bf16x8*)(Wp + (size_t)(((ct0+0)*8 + ks)*64 + lane) * 8);
    wf[ks*2+1] = *(const bf16x8*)(Wp + (size_t)(((ct0+1)*8 + ks)*64 + lane) * 8);
  }
  bf16x8 Hb0[4], Hb1[4];
  #pragma unroll
  for (int ks = 0; ks < 4; ks++){
    int kloc = ks*32 + quad*8;
    Hb0[ks] = *(const bf16x8*)(hself + (size_t)(row0 + rlo) * DD + kloc);
    Hb1[ks] = *(const bf16x8*)(hself + (size_t)(row0 + 16 + rlo) * DD + kloc);
  }
  bf16x8 Mb0[4], Mb1[4];
  #pragma unroll
  for (int ks2 = 0; ks2 < 4; ks2++){
    int c8 = ks2*4 + quad;               // 16B chunk index 0..15
    int lr0 = rlo, lr1 = 16 + rlo;
    Mb0[ks2] = *(const bf16x8*)(msgT + lr0*DD + ((c8 ^ (lr0 & 7)) * 8));
    Mb1[ks2] = *(const bf16x8*)(msgT + lr1*DD + ((c8 ^ (lr1 & 7)) * 8));
  }

  f32x4 acc[2][2];
  #pragma unroll
  for (int i = 0; i < 2; i++)
    #pragma unroll
    for (int j = 0; j < 2; j++){ f32x4 z = {0.f,0.f,0.f,0.f}; acc[i][j] = z; }

  #pragma unroll
  for (int ks = 0; ks < 4; ks++){
    acc[0][0] = __builtin_amdgcn_mfma_f32_16x16x32_bf16(wf[ks*2+0], Hb0[ks], acc[0][0], 0, 0, 0);
    acc[0][1] = __builtin_amdgcn_mfma_f32_16x16x32_bf16(wf[ks*2+1], Hb0[ks], acc[0][1], 0, 0, 0);
    acc[1][0] = __builtin_amdgcn_mfma_f32_16x16x32_bf16(wf[ks*2+0], Hb1[ks], acc[1][0], 0, 0, 0);
    acc[1][1] = __builtin_amdgcn_mfma_f32_16x16x32_bf16(wf[ks*2+1], Hb1[ks], acc[1][1], 0, 0, 0);
  }
  #pragma unroll
  for (int ks2 = 0; ks2 < 4; ks2++){
    int ks = 4 + ks2;
    acc[0][0] = __builtin_amdgcn_mfma_f32_16x16x32_bf16(wf[ks*2+0], Mb0[ks2], acc[0][0], 0, 0, 0);
    acc[0][1] = __builtin_amdgcn_mfma_f32_16x16x32_bf16(wf[ks*2+1], Mb0[ks2], acc[0][1], 0, 0, 0);
    acc[1][0] = __builtin_amdgcn_mfma_f32_16x16x32_bf16(wf[ks*2+0], Mb1[ks2], acc[1][0], 0, 0, 0);
    acc[1][1] = __builtin_amdgcn_mfma_f32_16x16x32_bf16(wf[ks*2+1], Mb1[ks2], acc[1][1], 0, 0, 0);
  }

  // epilogue: acc[rb][c][i] = out[row0+rb*16+rlo][(ct0+c)*16 + quad*4 + i]
  #pragma unroll
  for (int c = 0; c < 2; c++){
    float4 bv = *(const float4*)(bias + (ct0+c)*16 + quad*4);
    #pragma unroll
    for (int rb = 0; rb < 2; rb++){
      int row = row0 + rb*16 + rlo;
      float v0 = acc[rb][c][0] + bv.x;
      float v1 = acc[rb][c][1] + bv.y;
      float v2 = acc[rb][c][2] + bv.z;
      float v3 = acc[rb][c][3] + bv.w;
      v0 = v0 > 0.f ? v0 : 0.f;
      v1 = v1 > 0.f ? v1 : 0.f;
      v2 = v2 > 0.f ? v2 : 0.f;
      v3 = v3 > 0.f ? v3 : 0.f;
      u32x2 o; o.x = packbf(v0, v1); o.y = packbf(v2, v3);
      *(u32x2*)(hout + (size_t)row*DD + (ct0+c)*16 + quad*4) = o;
    }
  }
}

// ---------------- segment-mean pooling: 16B loads, 2-stage reduce ----------------
__global__ __launch_bounds__(256) void pool(const unsigned short* __restrict__ hs,
        const unsigned short* __restrict__ hr, float* __restrict__ out){
  __shared__ float red[16][128];
  int b = blockIdx.x, part = blockIdx.y;   // part<4: species, else reactions (500 rows each)
  int t = threadIdx.x;
  int rg = t >> 4, sub = t & 15;
  const unsigned short* src; int row0, outoff; float scale;
  if (part < 4){ src = hs; row0 = b*NSP + part*500; outoff = b*256; scale = 1.f/NSP; }
  else { src = hr; row0 = b*NRP + (part-4)*500; outoff = b*256 + 128; scale = 1.f/NRP; }
  float a0=0,a1=0,a2=0,a3=0,a4=0,a5=0,a6=0,a7=0;
  for (int r = rg; r < 500; r += 16){
    u32x4 p = *(const u32x4*)(src + (size_t)(row0+r)*DD + sub*8);
    a0 += bflo(p.x); a1 += bfhi(p.x);
    a2 += bflo(p.y); a3 += bfhi(p.y);
    a4 += bflo(p.z); a5 += bfhi(p.z);
    a6 += bflo(p.w); a7 += bfhi(p.w);
  }
  float* rr = &red[rg][sub*8];
  rr[0]=a0; rr[1]=a1; rr[2]=a2; rr[3]=a3; rr[4]=a4; rr[5]=a5; rr[6]=a6; rr[7]=a7;
  __syncthreads();
  if (t < 128){
    float s = 0.f;
    #pragma unroll
    for (int g = 0; g < 16; g++) s += red[g][t];
    atomicAdd(&out[outoff + t], s * scale);
  }
}

extern "C" void kernel_launch(void* const* d_in, const int* in_sizes, int n_in,
                              void* d_out, int out_size, void* d_ws, size_t ws_size,
                              hipStream_t stream)
{
  const int*   si   = (const int*)d_in[0];
  const int*   ext  = (const int*)d_in[1];
  const int*   tid  = (const int*)d_in[2];
  const float* pp   = (const float*)d_in[3];
  const int*   es   = (const int*)d_in[4];
  const int*   er   = (const int*)d_in[5];
  const float* st   = (const float*)d_in[8];
  const float* et   = (const float*)d_in[9];
  const float* tt   = (const float*)d_in[10];
  const float* Wpar = (const float*)d_in[11];
  const float* bpar = (const float*)d_in[12];
  const float* Wr   = (const float*)d_in[13];
  const float* br   = (const float*)d_in[14];
  const float* Ws   = (const float*)d_in[15];
  const float* bs   = (const float*)d_in[16];
  float* out = (float*)d_out;

  char* basep = (char*)d_ws; size_t off = 0;
  auto alloc = [&](size_t bytes)->char*{
    char* r = basep + off; off = (off + bytes + 255) & ~(size_t)255; return r;
  };
  unsigned short* hs0 = (unsigned short*)alloc((size_t)NS*DD*2);
  unsigned short* hs1 = (unsigned short*)alloc((size_t)NS*DD*2);
  unsigned short* hr0 = (unsigned short*)alloc((size_t)NR*DD*2);
  unsigned short* hr1 = (unsigned short*)alloc((size_t)NR*DD*2);
  unsigned short* Wp  = (unsigned short*)alloc((size_t)4*32768*2);
  int* offsR = (int*)alloc((size_t)(NR+1)*4);
  int* offsS = (int*)alloc((size_t)(NS+1)*4);
  unsigned* csrR = (unsigned*)alloc((size_t)EE*4);
  unsigned* csrS = (unsigned*)alloc((size_t)EE*4);
  int* gcnt   = (int*)alloc(2048);
  int* bktOffR= (int*)alloc(2048);
  int* bktOffS= (int*)alloc(2048);
  int* gCurR  = (int*)alloc(2048);
  int* gCurS  = (int*)alloc(2048);
  // rec arrays only live during CSR build; alias into the ping buffers
  // (hs1 / hr1 are first written at layer-0 fused dispatches, after build_csr).
  unsigned* recR = (unsigned*)hs1;            // 4 MB within 25.6 MB
  unsigned* recS = (unsigned*)hr1;            // 4 MB within 51.2 MB

  hipMemsetAsync(gcnt, 0, 2048, stream);
  hipMemsetAsync(d_out, 0, (size_t)out_size*4, stream);

  pack_w<<<512, 256, 0, stream>>>(Wr, Ws, Wp);
  init_all<<<(NS+NR)*16/256, 256, 0, stream>>>(si, ext, tid, pp, st, et, tt, Wpar, bpar, hs0, hr0);

  bucket_hist<<<(EE + 2047)/2048, 256, 0, stream>>>(er, es, gcnt);
  bucket_scan<<<1, 256, 0, stream>>>(gcnt, bktOffR, bktOffS, gCurR, gCurS);
  bin_edges<<<dim3((EE + CHUNK - 1)/CHUNK, 2), 256, 0, stream>>>(er, es, gCurR, gCurS, recR, recS);
  build_csr<<<NBR + NBS, 256, 0, stream>>>(recR, recS, bktOffR, bktOffS, csrR, csrS, offsR, offsS);

  // layer 0
  fused_layer<<<NR/32, 256, 0, stream>>>(hs0, hr0, offsR, csrR, Wp + (size_t)0*32768, br + (size_t)0*DD, hr1);
  fused_layer<<<NS/32, 256, 0, stream>>>(hr1, hs0, offsS, csrS, Wp + (size_t)2*32768, bs + (size_t)0*DD, hs1);
  // layer 1
  fused_layer<<<NR/32, 256, 0, stream>>>(hs1, hr1, offsR, csrR, Wp + (size_t)1*32768, br + (size_t)1*DD, hr0);
  fused_layer<<<NS/32, 256, 0, stream>>>(hr0, hs1, offsS, csrS, Wp + (size_t)3*32768, bs + (size_t)1*DD, hs0);

  pool<<<dim3(NB, 12), 256, 0, stream>>>(hs0, hr0, out);
}

// Round 9
// 465.105 us; speedup vs baseline: 1.3782x; 1.0265x over previous
//
#include <hip/hip_runtime.h>
#include <stdint.h>

#define NS 100000
#define NR 200000
#define EE 1000000
#define DD 128
#define NB 50
#define NSP 2000
#define NRP 4000
#define BSH 10
#define NBR 196   /* ceil(NR/1024) */
#define NBS 98    /* ceil(NS/1024) */
#define CHUNK 8192

typedef short bf16x8 __attribute__((ext_vector_type(8)));
typedef float f32x4 __attribute__((ext_vector_type(4)));
typedef unsigned u32x4 __attribute__((ext_vector_type(4)));
typedef unsigned u32x2 __attribute__((ext_vector_type(2)));

__device__ __forceinline__ unsigned short f2bf(float f){
  unsigned u = __float_as_uint(f);
  u = (u + 0x7FFFu + ((u >> 16) & 1u)) >> 16;
  return (unsigned short)u;
}
__device__ __forceinline__ unsigned packbf(float a, float b){
  return (unsigned)f2bf(a) | ((unsigned)f2bf(b) << 16);
}
__device__ __forceinline__ float bflo(unsigned p){ return __uint_as_float(p << 16); }
__device__ __forceinline__ float bfhi(unsigned p){ return __uint_as_float(p & 0xFFFF0000u); }

// ---------------- weight pre-pack into MFMA fragment order ----------------
// Wp[mat][ct][ks][lane][j] = W[mat][k = ks*32 + (lane>>4)*8 + j][col = ct*16 + (lane&15)]
__global__ void pack_w(const float* __restrict__ Wr, const float* __restrict__ Ws,
                       unsigned short* __restrict__ Wp){
  int g = blockIdx.x*256 + threadIdx.x;   // 4*32768 = 131072 total
  if (g >= 4*32768) return;
  int j = g & 7; int rest = g >> 3;
  int lane = rest & 63; rest >>= 6;
  int ks = rest & 7; rest >>= 3;
  int ct = rest & 7; int mat = rest >> 3;
  int k  = ks*32 + (lane >> 4)*8 + j;
  int cc = ct*16 + (lane & 15);
  const float* src = (mat < 2) ? (Wr + (size_t)mat*256*DD) : (Ws + (size_t)(mat-2)*256*DD);
  Wp[g] = f2bf(src[(size_t)k*DD + cc]);
}

// ---------------- layer-0 dedup gather table: 4000 rows (1 MB, L2-resident) ----
// gtab[(i*2+e)] = species_table[i] + external_table[e]  (same bf16 rounding as hs0)
__global__ __launch_bounds__(256) void build_gtab(const float* __restrict__ st,
        const float* __restrict__ et, unsigned short* __restrict__ gtab){
  int g = blockIdx.x*256 + threadIdx.x;   // 4000*16 total
  if (g >= 4000*16) return;
  int row = g >> 4, colb = (g & 15) * 8;
  int i = row >> 1, e = row & 1;
  const float* a = st + (size_t)i*DD + colb;
  const float* b = et + (size_t)e*DD + colb;
  float4 x0 = ((const float4*)a)[0], x1 = ((const float4*)a)[1];
  float4 y0 = ((const float4*)b)[0], y1 = ((const float4*)b)[1];
  u32x4 o;
  o.x = packbf(x0.x+y0.x, x0.y+y0.y);
  o.y = packbf(x0.z+y0.z, x0.w+y0.w);
  o.z = packbf(x1.x+y1.x, x1.y+y1.y);
  o.w = packbf(x1.z+y1.z, x1.w+y1.w);
  *(u32x4*)(gtab + (size_t)row*DD + colb) = o;
}

// ---------------- fused embedding init: 16B stores, float4 reads ----------------
// Also writes didx[s] = byte offset of species s's row in gtab (dedup index).
__global__ __launch_bounds__(256) void init_all(const int* __restrict__ si, const int* __restrict__ ext,
        const int* __restrict__ tid, const float* __restrict__ pp,
        const float* __restrict__ st, const float* __restrict__ et, const float* __restrict__ tt,
        const float* __restrict__ Wpar, const float* __restrict__ bpar,
        unsigned short* __restrict__ hs, unsigned short* __restrict__ hr,
        unsigned* __restrict__ didx){
  int g = blockIdx.x*256 + threadIdx.x;   // (NS+NR)*16 total
  int row = g >> 4, colb = (g & 15) * 8;
  if (row < NS){
    int siv = si[row], exv = ext[row];
    if ((g & 15) == 0) didx[row] = (unsigned)(((siv << 1) | exv) << 8);
    const float* a = st + (size_t)siv*DD + colb;
    const float* b = et + (size_t)exv*DD + colb;
    float4 x0 = ((const float4*)a)[0], x1 = ((const float4*)a)[1];
    float4 y0 = ((const float4*)b)[0], y1 = ((const float4*)b)[1];
    u32x4 o;
    o.x = packbf(x0.x+y0.x, x0.y+y0.y);
    o.y = packbf(x0.z+y0.z, x0.w+y0.w);
    o.z = packbf(x1.x+y1.x, x1.y+y1.y);
    o.w = packbf(x1.z+y1.z, x1.w+y1.w);
    *(u32x4*)(hs + (size_t)row*DD + colb) = o;
  } else {
    int r = row - NS;
    const float* tb = tt + (size_t)tid[r]*DD + colb;
    float4 a0 = ((const float4*)tb)[0], a1 = ((const float4*)tb)[1];
    float4 b0 = ((const float4*)(bpar+colb))[0], b1 = ((const float4*)(bpar+colb))[1];
    a0.x += b0.x; a0.y += b0.y; a0.z += b0.z; a0.w += b0.w;
    a1.x += b1.x; a1.y += b1.y; a1.z += b1.z; a1.w += b1.w;
    const float* pr = pp + (size_t)r*8;
    float4 p0 = ((const float4*)pr)[0], p1 = ((const float4*)pr)[1];
    float w[8] = {p0.x,p0.y,p0.z,p0.w,p1.x,p1.y,p1.z,p1.w};
    #pragma unroll
    for (int p = 0; p < 8; p++){
      float4 w0 = ((const float4*)(Wpar + p*DD + colb))[0];
      float4 w1 = ((const float4*)(Wpar + p*DD + colb))[1];
      a0.x += w[p]*w0.x; a0.y += w[p]*w0.y; a0.z += w[p]*w0.z; a0.w += w[p]*w0.w;
      a1.x += w[p]*w1.x; a1.y += w[p]*w1.y; a1.z += w[p]*w1.z; a1.w += w[p]*w1.w;
    }
    u32x4 o;
    o.x = packbf(a0.x, a0.y); o.y = packbf(a0.z, a0.w);
    o.z = packbf(a1.x, a1.y); o.w = packbf(a1.z, a1.w);
    *(u32x4*)(hr + (size_t)r*DD + colb) = o;
  }
}

// ---------------- bucketed CSR build ----------------
__global__ __launch_bounds__(256) void bucket_hist(const int* __restrict__ er, const int* __restrict__ es,
                                                   int* __restrict__ gcnt){
  __shared__ int cnt[NBR + NBS];
  int t = threadIdx.x;
  for (int j = t; j < NBR + NBS; j += 256) cnt[j] = 0;
  __syncthreads();
  long i0 = (long)blockIdx.x * 2048;
  for (int j = t; j < 2048; j += 256){
    long i = i0 + j;
    if (i < EE){
      atomicAdd(&cnt[er[i] >> BSH], 1);
      atomicAdd(&cnt[NBR + (es[i] >> BSH)], 1);
    }
  }
  __syncthreads();
  for (int j = t; j < NBR + NBS; j += 256)
    if (cnt[j]) atomicAdd(&gcnt[j], cnt[j]);
}

__global__ __launch_bounds__(256) void bucket_scan(const int* __restrict__ gcnt,
        int* __restrict__ bktOffR, int* __restrict__ bktOffS,
        int* __restrict__ gCurR, int* __restrict__ gCurS){
  __shared__ int a[256];
  int t = threadIdx.x;
  int own = (t < NBR) ? gcnt[t] : 0;
  a[t] = own; __syncthreads();
  for (int d = 1; d < 256; d <<= 1){
    int x = (t >= d) ? a[t-d] : 0;
    __syncthreads(); a[t] += x; __syncthreads();
  }
  if (t < NBR){ int v = a[t] - own; bktOffR[t] = v; gCurR[t] = v; }
  if (t == 0) bktOffR[NBR] = EE;
  __syncthreads();
  own = (t < NBS) ? gcnt[NBR + t] : 0;
  a[t] = own; __syncthreads();
  for (int d = 1; d < 256; d <<= 1){
    int x = (t >= d) ? a[t-d] : 0;
    __syncthreads(); a[t] += x; __syncthreads();
  }
  if (t < NBS){ int v = a[t] - own; bktOffS[t] = v; gCurS[t] = v; }
  if (t == 0) bktOffS[NBS] = EE;
}

__global__ __launch_bounds__(256) void bin_edges(const int* __restrict__ er, const int* __restrict__ es,
        int* __restrict__ gCurR, int* __restrict__ gCurS,
        unsigned* __restrict__ recR, unsigned* __restrict__ recS){
  __shared__ unsigned stage[CHUNK];
  __shared__ unsigned char stageb[CHUNK];
  __shared__ int cnt[256], scn[256], pref[256], gbase[256], lcur[256];
  int t = threadIdx.x;
  int side = blockIdx.y;
  const int* dest = side ? es : er;
  const int* srca = side ? er : es;
  int* gCur = side ? gCurS : gCurR;
  unsigned* rec = side ? recS : recR;
  int nbkt = side ? NBS : NBR;
  long i0 = (long)blockIdx.x * CHUNK;
  int n = (EE - i0 < CHUNK) ? (int)(EE - i0) : CHUNK;
  cnt[t] = 0;
  __syncthreads();
  for (int j = t; j < n; j += 256)
    atomicAdd(&cnt[dest[i0 + j] >> BSH], 1);
  __syncthreads();
  scn[t] = cnt[t];
  __syncthreads();
  for (int d = 1; d < 256; d <<= 1){
    int x = (t >= d) ? scn[t-d] : 0;
    __syncthreads(); scn[t] += x; __syncthreads();
  }
  pref[t] = scn[t] - cnt[t];
  lcur[t] = scn[t] - cnt[t];
  if (t < nbkt && cnt[t] > 0) gbase[t] = atomicAdd(&gCur[t], cnt[t]);
  __syncthreads();
  for (int j = t; j < n; j += 256){
    int d = dest[i0 + j];
    int s = srca[i0 + j];
    int b = d >> BSH;
    int p = atomicAdd(&lcur[b], 1);
    stage[p] = ((unsigned)(d - (b << BSH)) << 18) | (unsigned)s;
    stageb[p] = (unsigned char)b;
  }
  __syncthreads();
  for (int e = t; e < n; e += 256){
    int b = stageb[e];
    rec[gbase[b] + (e - pref[b])] = stage[e];
  }
}

// Stage 4: scatter PRESCALED records: (dloc<<26) | (src*256)  [src byte offset]
// R-side additionally writes csr0R with the LAYER-0 DEDUP source offset
// (didx[src] -> row in the 4000-entry gtab).
__global__ __launch_bounds__(256) void build_csr(const unsigned* __restrict__ recR, const unsigned* __restrict__ recS,
        const int* __restrict__ bktOffR, const int* __restrict__ bktOffS,
        unsigned* __restrict__ csrR, unsigned* __restrict__ csrS,
        int* __restrict__ offsR, int* __restrict__ offsS,
        const unsigned* __restrict__ didx, unsigned* __restrict__ csr0R){
  __shared__ int hist[1024], pref[1024], cur[1024], ws[256];
  int t = threadIdx.x;
  int bb = blockIdx.x;
  const unsigned* rec; const int* bktOff; unsigned* csr; int* offs; int N; int isR;
  if (bb < NBR){ rec = recR; bktOff = bktOffR; csr = csrR; offs = offsR; N = NR; isR = 1; }
  else { bb -= NBR; rec = recS; bktOff = bktOffS; csr = csrS; offs = offsS; N = NS; isR = 0; }
  int d0 = bb << BSH;
  int base = bktOff[bb], cnt_ = bktOff[bb+1] - base;
  #pragma unroll
  for (int j = 0; j < 4; j++) hist[t*4+j] = 0;
  __syncthreads();
  for (int e = t; e < cnt_; e += 256)
    atomicAdd(&hist[rec[base + e] >> 18], 1);
  __syncthreads();
  int s = 0, h[4];
  #pragma unroll
  for (int j = 0; j < 4; j++){ h[j] = hist[t*4+j]; s += h[j]; }
  ws[t] = s;
  __syncthreads();
  for (int d = 1; d < 256; d <<= 1){
    int x = (t >= d) ? ws[t-d] : 0;
    __syncthreads(); ws[t] += x; __syncthreads();
  }
  int run = ws[t] - s;
  #pragma unroll
  for (int j = 0; j < 4; j++){ pref[t*4+j] = run; cur[t*4+j] = base + run; run += h[j]; }
  __syncthreads();
  int DPB = N - d0; if (DPB > 1024) DPB = 1024;
  #pragma unroll
  for (int j = 0; j < 4; j++){
    int i = t*4 + j;
    if (i < DPB) offs[d0 + i] = base + pref[i];
  }
  if (t == 0 && d0 + DPB == N) offs[N] = EE;
  __syncthreads();
  for (int e = t; e < cnt_; e += 256){
    unsigned r = rec[base + e];
    int pos = atomicAdd(&cur[r >> 18], 1);
    unsigned dl = ((r >> 18) & 31u) << 26;
    csr[pos] = dl | ((r & 0x3FFFFu) << 8);            // dloc<<26 | src byte-offset
    if (isR) csr0R[pos] = dl | didx[r & 0x3FFFFu];    // dloc<<26 | gtab byte-offset
  }
}

// ============ fused streaming-gather + concat-GEMM + bias + relu ============
// R9: fused_layer restored to the proven R0 structure (best measured: 72 us,
// absmax 0.0625). R1-R8 established the gather cost is invariant to
// scheduling depth, bytes/instr, and instr/edge for L2-MISS sources.
// Dispatch 1 now gathers from the 1 MB L2-RESIDENT gtab (4000 distinct
// layer-0 species rows) via csr0R -- the one untested variable (hit tier).
__global__ __launch_bounds__(256) void fused_layer(
        const unsigned short* __restrict__ gsrc,   // gather source rows (bf16)
        const unsigned short* __restrict__ hself,  // self features (bf16)
        const int* __restrict__ offs, const unsigned* __restrict__ csr,
        const unsigned short* __restrict__ Wp, const float* __restrict__ bias,
        unsigned short* __restrict__ hout)
{
  __shared__ unsigned short msgT[32*DD];   // 8 KB; 16B chunks swizzled: slot = c16 ^ (row&7)
  int t = threadIdx.x;
  int lane = t & 63;
  int w = t >> 6;
  int quad = lane >> 4, rlo = lane & 15;
  int row0 = blockIdx.x * 32;

  // zero-init msg tile (covers empty rows)
  for (int i = t; i < 2048; i += 256) ((unsigned*)msgT)[i] = 0u;
  __syncthreads();

  // ---- phase 1: wave streams the edges of its 8 rows (scalar control) ----
  {
    int rbeg = row0 + w*8;
    int k  = __builtin_amdgcn_readfirstlane(offs[rbeg]);
    int ke = __builtin_amdgcn_readfirstlane(offs[rbeg + 8]);
    int c16 = lane >> 2, sub4 = lane & 3;
    const char* gbase = (const char*)gsrc;
    float a0 = 0.f, a1 = 0.f;
    int cur = -1;
    unsigned rc[8]; unsigned pv[8];
    if (k < ke){
      #pragma unroll
      for (int i = 0; i < 8; i++){
        int kk = (k + i < ke) ? (k + i) : (ke - 1);
        rc[i] = (unsigned)__builtin_amdgcn_readfirstlane(csr[kk]);   // SGPR record
      }
      #pragma unroll
      for (int i = 0; i < 8; i++)
        pv[i] = *(const unsigned*)(gbase + (rc[i] & 0x03FFFF00u) + lane*4);  // saddr + v_off
      while (k < ke){
        unsigned rc2[8], pv2[8];
        int kn = k + 8;
        #pragma unroll
        for (int i = 0; i < 8; i++){
          int kk = (kn + i < ke) ? (kn + i) : (ke - 1);
          rc2[i] = (unsigned)__builtin_amdgcn_readfirstlane(csr[kk]);
        }
        #pragma unroll
        for (int i = 0; i < 8; i++)
          pv2[i] = *(const unsigned*)(gbase + (rc2[i] & 0x03FFFF00u) + lane*4);
        #pragma unroll
        for (int i = 0; i < 8; i++){
          if (k + i < ke){                            // scalar compare (k,ke,i uniform)
            int dl = (int)(rc[i] >> 26);              // scalar
            if (dl != cur){                           // scalar branch
              if (cur >= 0)
                *(unsigned*)(msgT + cur*DD + ((c16 ^ (cur & 7)) << 3) + (sub4 << 1)) = packbf(a0, a1);
              a0 = 0.f; a1 = 0.f;
              cur = dl;
            }
            a0 += bflo(pv[i]); a1 += bfhi(pv[i]);
          }
        }
        #pragma unroll
        for (int i = 0; i < 8; i++){ rc[i] = rc2[i]; pv[i] = pv2[i]; }
        k = kn;
      }
      if (cur >= 0)
        *(unsigned*)(msgT + cur*DD + ((c16 ^ (cur & 7)) << 3) + (sub4 << 1)) = packbf(a0, a1);
    }
  }
  __syncthreads();

  // ---- phase 2: MFMA. W = A-operand, H/msg = B-operand. Wave -> 32-col strip. ----
  int ct0 = w * 2;
  bf16x8 wf[16];                         // [ks][c]
  #pragma unroll
  for (int ks = 0; ks < 8; ks++){
    wf[ks*2+0] = *(const bf16x8*)(Wp + (size_t)(((ct0+0)*8 + ks)*64 + lane) * 8);
    wf[ks*2+1] = *(const bf16x8*)(Wp + (size_t)(((ct0+1)*8 + ks)*64 + lane) * 8);
  }
  bf16x8 Hb0[4], Hb1[4];
  #pragma unroll
  for (int ks = 0; ks < 4; ks++){
    int kloc = ks*32 + quad*8;
    Hb0[ks] = *(const bf16x8*)(hself + (size_t)(row0 + rlo) * DD + kloc);
    Hb1[ks] = *(const bf16x8*)(hself + (size_t)(row0 + 16 + rlo) * DD + kloc);
  }
  bf16x8 Mb0[4], Mb1[4];
  #pragma unroll
  for (int ks2 = 0; ks2 < 4; ks2++){
    int c8 = ks2*4 + quad;               // 16B chunk index 0..15
    int lr0 = rlo, lr1 = 16 + rlo;
    Mb0[ks2] = *(const bf16x8*)(msgT + lr0*DD + ((c8 ^ (lr0 & 7)) * 8));
    Mb1[ks2] = *(const bf16x8*)(msgT + lr1*DD + ((c8 ^ (lr1 & 7)) * 8));
  }

  f32x4 acc[2][2];
  #pragma unroll
  for (int i = 0; i < 2; i++)
    #pragma unroll
    for (int j = 0; j < 2; j++){ f32x4 z = {0.f,0.f,0.f,0.f}; acc[i][j] = z; }

  #pragma unroll
  for (int ks = 0; ks < 4; ks++){
    acc[0][0] = __builtin_amdgcn_mfma_f32_16x16x32_bf16(wf[ks*2+0], Hb0[ks], acc[0][0], 0, 0, 0);
    acc[0][1] = __builtin_amdgcn_mfma_f32_16x16x32_bf16(wf[ks*2+1], Hb0[ks], acc[0][1], 0, 0, 0);
    acc[1][0] = __builtin_amdgcn_mfma_f32_16x16x32_bf16(wf[ks*2+0], Hb1[ks], acc[1][0], 0, 0, 0);
    acc[1][1] = __builtin_amdgcn_mfma_f32_16x16x32_bf16(wf[ks*2+1], Hb1[ks], acc[1][1], 0, 0, 0);
  }
  #pragma unroll
  for (int ks2 = 0; ks2 < 4; ks2++){
    int ks = 4 + ks2;
    acc[0][0] = __builtin_amdgcn_mfma_f32_16x16x32_bf16(wf[ks*2+0], Mb0[ks2], acc[0][0], 0, 0, 0);
    acc[0][1] = __builtin_amdgcn_mfma_f32_16x16x32_bf16(wf[ks*2+1], Mb0[ks2], acc[0][1], 0, 0, 0);
    acc[1][0] = __builtin_amdgcn_mfma_f32_16x16x32_bf16(wf[ks*2+0], Mb1[ks2], acc[1][0], 0, 0, 0);
    acc[1][1] = __builtin_amdgcn_mfma_f32_16x16x32_bf16(wf[ks*2+1], Mb1[ks2], acc[1][1], 0, 0, 0);
  }

  // epilogue: acc[rb][c][i] = out[row0+rb*16+rlo][(ct0+c)*16 + quad*4 + i]
  #pragma unroll
  for (int c = 0; c < 2; c++){
    float4 bv = *(const float4*)(bias + (ct0+c)*16 + quad*4);
    #pragma unroll
    for (int rb = 0; rb < 2; rb++){
      int row = row0 + rb*16 + rlo;
      float v0 = acc[rb][c][0] + bv.x;
      float v1 = acc[rb][c][1] + bv.y;
      float v2 = acc[rb][c][2] + bv.z;
      float v3 = acc[rb][c][3] + bv.w;
      v0 = v0 > 0.f ? v0 : 0.f;
      v1 = v1 > 0.f ? v1 : 0.f;
      v2 = v2 > 0.f ? v2 : 0.f;
      v3 = v3 > 0.f ? v3 : 0.f;
      u32x2 o; o.x = packbf(v0, v1); o.y = packbf(v2, v3);
      *(u32x2*)(hout + (size_t)row*DD + (ct0+c)*16 + quad*4) = o;
    }
  }
}

// ---------------- segment-mean pooling: 16B loads, 2-stage reduce ----------------
__global__ __launch_bounds__(256) void pool(const unsigned short* __restrict__ hs,
        const unsigned short* __restrict__ hr, float* __restrict__ out){
  __shared__ float red[16][128];
  int b = blockIdx.x, part = blockIdx.y;   // part<4: species, else reactions (500 rows each)
  int t = threadIdx.x;
  int rg = t >> 4, sub = t & 15;
  const unsigned short* src; int row0, outoff; float scale;
  if (part < 4){ src = hs; row0 = b*NSP + part*500; outoff = b*256; scale = 1.f/NSP; }
  else { src = hr; row0 = b*NRP + (part-4)*500; outoff = b*256 + 128; scale = 1.f/NRP; }
  float a0=0,a1=0,a2=0,a3=0,a4=0,a5=0,a6=0,a7=0;
  for (int r = rg; r < 500; r += 16){
    u32x4 p = *(const u32x4*)(src + (size_t)(row0+r)*DD + sub*8);
    a0 += bflo(p.x); a1 += bfhi(p.x);
    a2 += bflo(p.y); a3 += bfhi(p.y);
    a4 += bflo(p.z); a5 += bfhi(p.z);
    a6 += bflo(p.w); a7 += bfhi(p.w);
  }
  float* rr = &red[rg][sub*8];
  rr[0]=a0; rr[1]=a1; rr[2]=a2; rr[3]=a3; rr[4]=a4; rr[5]=a5; rr[6]=a6; rr[7]=a7;
  __syncthreads();
  if (t < 128){
    float s = 0.f;
    #pragma unroll
    for (int g = 0; g < 16; g++) s += red[g][t];
    atomicAdd(&out[outoff + t], s * scale);
  }
}

extern "C" void kernel_launch(void* const* d_in, const int* in_sizes, int n_in,
                              void* d_out, int out_size, void* d_ws, size_t ws_size,
                              hipStream_t stream)
{
  const int*   si   = (const int*)d_in[0];
  const int*   ext  = (const int*)d_in[1];
  const int*   tid  = (const int*)d_in[2];
  const float* pp   = (const float*)d_in[3];
  const int*   es   = (const int*)d_in[4];
  const int*   er   = (const int*)d_in[5];
  const float* st   = (const float*)d_in[8];
  const float* et   = (const float*)d_in[9];
  const float* tt   = (const float*)d_in[10];
  const float* Wpar = (const float*)d_in[11];
  const float* bpar = (const float*)d_in[12];
  const float* Wr   = (const float*)d_in[13];
  const float* br   = (const float*)d_in[14];
  const float* Ws   = (const float*)d_in[15];
  const float* bs   = (const float*)d_in[16];
  float* out = (float*)d_out;

  char* basep = (char*)d_ws; size_t off = 0;
  auto alloc = [&](size_t bytes)->char*{
    char* r = basep + off; off = (off + bytes + 255) & ~(size_t)255; return r;
  };
  unsigned short* hs0 = (unsigned short*)alloc((size_t)NS*DD*2);
  unsigned short* hs1 = (unsigned short*)alloc((size_t)NS*DD*2);
  unsigned short* hr0 = (unsigned short*)alloc((size_t)NR*DD*2);
  unsigned short* hr1 = (unsigned short*)alloc((size_t)NR*DD*2);
  unsigned short* Wp  = (unsigned short*)alloc((size_t)4*32768*2);
  int* offsR = (int*)alloc((size_t)(NR+1)*4);
  int* offsS = (int*)alloc((size_t)(NS+1)*4);
  unsigned* csrR  = (unsigned*)alloc((size_t)EE*4);
  unsigned* csrS  = (unsigned*)alloc((size_t)EE*4);
  unsigned* csr0R = (unsigned*)alloc((size_t)EE*4);          // layer-0 dedup records
  unsigned short* gtab = (unsigned short*)alloc((size_t)4000*DD*2);  // 1 MB table
  unsigned* didx  = (unsigned*)alloc((size_t)NS*4);
  int* gcnt   = (int*)alloc(2048);
  int* bktOffR= (int*)alloc(2048);
  int* bktOffS= (int*)alloc(2048);
  int* gCurR  = (int*)alloc(2048);
  int* gCurS  = (int*)alloc(2048);
  // rec arrays only live during CSR build; alias into the ping buffers
  // (hs1 / hr1 are first written at layer-0 fused dispatches, after build_csr).
  unsigned* recR = (unsigned*)hs1;            // 4 MB within 25.6 MB
  unsigned* recS = (unsigned*)hr1;            // 4 MB within 51.2 MB

  hipMemsetAsync(gcnt, 0, 2048, stream);
  hipMemsetAsync(d_out, 0, (size_t)out_size*4, stream);

  pack_w<<<512, 256, 0, stream>>>(Wr, Ws, Wp);
  init_all<<<(NS+NR)*16/256, 256, 0, stream>>>(si, ext, tid, pp, st, et, tt, Wpar, bpar, hs0, hr0, didx);
  build_gtab<<<(4000*16+255)/256, 256, 0, stream>>>(st, et, gtab);

  bucket_hist<<<(EE + 2047)/2048, 256, 0, stream>>>(er, es, gcnt);
  bucket_scan<<<1, 256, 0, stream>>>(gcnt, bktOffR, bktOffS, gCurR, gCurS);
  bin_edges<<<dim3((EE + CHUNK - 1)/CHUNK, 2), 256, 0, stream>>>(er, es, gCurR, gCurS, recR, recS);
  build_csr<<<NBR + NBS, 256, 0, stream>>>(recR, recS, bktOffR, bktOffS, csrR, csrS, offsR, offsS, didx, csr0R);

  // layer 0 (R-side gathers from the 1 MB L2-resident dedup table)
  fused_layer<<<NR/32, 256, 0, stream>>>(gtab, hr0, offsR, csr0R, Wp + (size_t)0*32768, br + (size_t)0*DD, hr1);
  fused_layer<<<NS/32, 256, 0, stream>>>(hr1, hs0, offsS, csrS, Wp + (size_t)2*32768, bs + (size_t)0*DD, hs1);
  // layer 1
  fused_layer<<<NR/32, 256, 0, stream>>>(hs1, hr1, offsR, csrR, Wp + (size_t)1*32768, br + (size_t)1*DD, hr0);
  fused_layer<<<NS/32, 256, 0, stream>>>(hr0, hs1, offsS, csrS, Wp + (size_t)3*32768, bs + (size_t)1*DD, hs0);

  pool<<<dim3(NB, 12), 256, 0, stream>>>(hs0, hr0, out);
}